// Round 1
// 301.392 us; speedup vs baseline: 1.0023x; 1.0023x over previous
//
#include <hip/hip_runtime.h>
#include <stdint.h>

#define BATCH 64
#define TLEN 1024
#define FDIM 1024

// Monotonic float->uint32 encoding: enc(a) > enc(b) iff a > b (no NaNs here).
__device__ __forceinline__ uint32_t fenc(float f) {
    uint32_t u = __float_as_uint(f);
    return (u & 0x80000000u) ? ~u : (u | 0x80000000u);
}

// Butterfly max across the 64-lane wave; every lane ends with the max.
__device__ __forceinline__ unsigned long long wave_max_u64(unsigned long long v) {
#pragma unroll
    for (int off = 32; off > 0; off >>= 1) {
        unsigned long long o = __shfl_xor(v, off, 64);
        if (o > v) v = o;
    }
    return v;
}

// Iterative top-K over keys held 16/lane (key = (fenc(val)<<32) | ~t).
// Winner is cleared by VALUE match in a fully-unrolled loop: no runtime
// indexing, so keys[] stays in VGPRs (rule #20 — runtime-indexed arrays
// demote to scratch).
template <int K>
__device__ __forceinline__ void topk_rounds(unsigned long long* keys, int* out_idx) {
#pragma unroll
    for (int i = 0; i < K; ++i) {
        unsigned long long m = 0;
#pragma unroll
        for (int j = 0; j < 16; ++j) if (keys[j] > m) m = keys[j];
        const unsigned long long w = wave_max_u64(m);
        out_idx[i] = (int)(~(unsigned)(w & 0xFFFFFFFFull));
        // keys are unique (low 32 bits = ~t) -> exactly one slot matches.
#pragma unroll
        for (int j = 0; j < 16; ++j) if (keys[j] == w) keys[j] = 0;
    }
}

// 4 blocks per batch (256 blocks x 256 threads). Each block redundantly runs
// the three tiny selections on waves 0..2 (deterministic -> identical sidx),
// then gathers its quarter (4 of the 16 rows) with all 4 waves. This puts the
// 8 MB gather on all 256 CUs instead of 64.
// LDS slot layout:
//   0      : hard normal (1)
//   1..3   : hard abnormal (3)
//   4..5   : confident normal (2)
//   6..15  : confident abnormal (10)
__global__ __launch_bounds__(256) void fused_kernel(
    const float* __restrict__ feat, const float* __restrict__ rgb,
    const float* __restrict__ flow, float* __restrict__ out)
{
    __shared__ int sidx[16];
    const int b = blockIdx.x >> 2;   // batch
    const int q = blockIdx.x & 3;    // quarter of the 16 slots
    const unsigned tid = threadIdx.x;
    const unsigned lane = tid & 63u;
    const unsigned wave = tid >> 6;  // 0..3

    if (wave < 3) {
        const float* s = rgb + b * TLEN;
        unsigned long long keys[16];
#pragma unroll
        for (int j = 0; j < 16; ++j) {
            const unsigned t = lane + 64u * j;
            const float x = s[t];
            const float v = (wave == 0) ? -fabsf(x - 0.5f) : (wave == 1) ? x : -x;
            keys[j] = ((unsigned long long)fenc(v) << 32) | (unsigned)(~t);
        }

        if (wave == 0) {
            // hard top-10 (closest to 0.5), then flow-based top3 / bottom1
            int hard_idx[10];
            topk_rounds<10>(keys, hard_idx);
            float hf[10];
#pragma unroll
            for (int k = 0; k < 10; ++k) hf[k] = flow[b * TLEN + hard_idx[k]];
            // top-3 of hard_flow (desc, tie -> lower k). Track the winning t
            // value directly so hard_idx[] is never runtime-indexed.
            int used = 0;
            int abn_t[3];
#pragma unroll
            for (int i = 0; i < 3; ++i) {
                int best = -1; float bv = 0.0f; int bt = 0;
#pragma unroll
                for (int k = 0; k < 10; ++k) {
                    const bool avail = !(used & (1 << k));
                    if (avail && (best < 0 || hf[k] > bv)) {
                        best = k; bv = hf[k]; bt = hard_idx[k];
                    }
                }
                abn_t[i] = bt; used |= (1 << best);
            }
            // bottom-1 of hard_flow (min, tie -> lower k)
            int nor_t = hard_idx[0]; float nv = hf[0];
#pragma unroll
            for (int k = 1; k < 10; ++k)
                if (hf[k] < nv) { nv = hf[k]; nor_t = hard_idx[k]; }
            if (lane == 0) {
                sidx[0] = nor_t;
                sidx[1] = abn_t[0];
                sidx[2] = abn_t[1];
                sidx[3] = abn_t[2];
            }
        } else if (wave == 1) {
            // confident abnormal: 10 largest rgb
            int ca[10];
            topk_rounds<10>(keys, ca);
            if (lane == 0) {
#pragma unroll
                for (int k = 0; k < 10; ++k) sidx[6 + k] = ca[k];
            }
        } else {
            // confident normal: 2 smallest rgb
            int cn[2];
            topk_rounds<2>(keys, cn);
            if (lane == 0) { sidx[4] = cn[0]; sidx[5] = cn[1]; }
        }
    }
    __syncthreads();

    // Gather this block's 4 rows: each thread copies one float4 per row
    // (256 threads x 16 B = 4 KB row, fully coalesced).
    const unsigned c = tid;  // float4 column within row, 0..255
#pragma unroll
    for (int s = 0; s < 4; ++s) {
        const int slot = q * 4 + s;
        const int t = sidx[slot];
        const float4* src =
            (const float4*)(feat + ((size_t)b * TLEN + t) * FDIM);
        size_t drow;
        if (slot == 0)       drow = (size_t)b;                       // [B,1,F]
        else if (slot <= 3)  drow = (size_t)(64 + b * 3 + (slot - 1));   // [B,3,F]
        else if (slot <= 5)  drow = (size_t)(256 + b * 2 + (slot - 4));  // [B,2,F]
        else                 drow = (size_t)(384 + b * 10 + (slot - 6)); // [B,10,F]
        ((float4*)(out + drow * FDIM))[c] = src[c];
    }
}

extern "C" void kernel_launch(void* const* d_in, const int* in_sizes, int n_in,
                              void* d_out, int out_size, void* d_ws, size_t ws_size,
                              hipStream_t stream) {
    const float* feat  = (const float*)d_in[0];   // [64,1024,1024] f32
    const float* s_rgb = (const float*)d_in[1];   // [64,1024] f32
    const float* s_flw = (const float*)d_in[2];   // [64,1024] f32
    float* out = (float*)d_out;                   // 1,048,576 f32

    fused_kernel<<<BATCH * 4, 256, 0, stream>>>(feat, s_rgb, s_flw, out);
}